// Round 9
// baseline (227.824 us; speedup 1.0000x reference)
//
#include <hip/hip_runtime.h>

#define DD 64
#define RR 16
#define EPSF 1e-9f
#define BINCH 4096        // edges per bin block (64-node buckets)

typedef unsigned short ushort_t;
typedef __bf16 bf16x8 __attribute__((ext_vector_type(8)));
typedef float f32x4 __attribute__((ext_vector_type(4)));
union F8 { uint4 u; bf16x8 v; };

__device__ __forceinline__ void fma4(float4& a, const float4& w, float s) {
    a.x = fmaf(w.x, s, a.x); a.y = fmaf(w.y, s, a.y);
    a.z = fmaf(w.z, s, a.z); a.w = fmaf(w.w, s, a.w);
}
__device__ __forceinline__ unsigned f2bf(float f) {
    unsigned u = __float_as_uint(f);
    return (u + 0x7FFFu + ((u >> 16) & 1u)) >> 16;   // RNE
}
__device__ __forceinline__ uint2 pk4(float4 v) {
    return make_uint2(f2bf(v.x) | (f2bf(v.y) << 16),
                      f2bf(v.z) | (f2bf(v.w) << 16));
}
__device__ __forceinline__ float bf_lo(unsigned u) { return __uint_as_float(u << 16); }
__device__ __forceinline__ float bf_hi(unsigned u) { return __uint_as_float(u & 0xFFFF0000u); }

// ---------------- prep: pack W1+W2, init cursors, emit self-loop records -------
__device__ __forceinline__ void packW_one(
    const float* __restrict__ W, ushort_t* __restrict__ Wb, int t)
{
    int lane = t & 63;
    int ot = (t >> 6) & 3;
    int kb = (t >> 8) & 1;
    int r  = t >> 9;
    int o  = ot * 16 + (lane & 15);
    int k0 = kb * 32 + (lane >> 4) * 8;
    const float* w = W + ((size_t)r * DD + k0) * DD + o;
    unsigned d[4];
    #pragma unroll
    for (int p = 0; p < 4; ++p)
        d[p] = f2bf(w[(2 * p) * DD]) | (f2bf(w[(2 * p + 1) * DD]) << 16);
    ((uint4*)Wb)[t] = make_uint4(d[0], d[1], d[2], d[3]);
}

__global__ __launch_bounds__(256) void k_prep(
    const float* __restrict__ W1, const float* __restrict__ W2,
    ushort_t* __restrict__ Wb1, ushort_t* __restrict__ Wb2,
    int* __restrict__ cursor, uint2* __restrict__ ep,
    const int* __restrict__ et, const float* __restrict__ pl,
    int B, int cap, int N, int E)
{
    int tid = blockIdx.x * 256 + threadIdx.x;
    if (tid < 8192)            packW_one(W1, Wb1, tid);
    else if (tid < 16384)      packW_one(W2, Wb2, tid - 8192);
    else if (tid < 16384 + B) {
        int b = tid - 16384;
        int nb = N - b * 64; if (nb > 64) nb = 64;
        cursor[b] = b * cap + nb;            // self records occupy the head
    } else if (tid < 16384 + B + N) {
        int n = tid - 16384 - B;
        int b = n >> 6;
        int idx = et[E + n] * N + n;         // rt*N+n < 2^20
        float iv = 1.0f / fmaxf(pl[E + n], EPSF);
        ep[(size_t)b * cap + (n & 63)] = make_uint2(
            (unsigned)idx | ((unsigned)(n & 63) << 20), __float_as_uint(iv));
    }
}

// ---------------- bin: direct segmented reservation ----------------------------
// rec = {(rt*N+src) | (dst&63)<<20, iv};  bucket b segment = [b*cap, (b+1)*cap)
__global__ __launch_bounds__(256) void k_bin(
    const int* __restrict__ ei, const int* __restrict__ et,
    const float* __restrict__ pl, int* __restrict__ cursor,
    uint2* __restrict__ ep, int E, int B, int N, int cap)
{
    __shared__ int hl[1024];
    __shared__ int bl[1024];
    for (int i = threadIdx.x; i < B; i += 256) hl[i] = 0;
    __syncthreads();
    const int e0 = blockIdx.x * BINCH;
    #pragma unroll 4
    for (int k = 0; k < BINCH / 256; ++k) {
        int e = e0 + k * 256 + threadIdx.x;
        if (e < E) atomicAdd(&hl[ei[E + e] >> 6], 1);
    }
    __syncthreads();
    for (int i = threadIdx.x; i < B; i += 256) {
        int c = hl[i];
        bl[i] = c ? atomicAdd(&cursor[i], c) : 0;
        hl[i] = 0;
    }
    __syncthreads();
    #pragma unroll 2
    for (int k = 0; k < BINCH / 256; ++k) {
        int e = e0 + k * 256 + threadIdx.x;
        if (e < E) {
            int dst = ei[E + e];
            int b = dst >> 6;
            int rank = atomicAdd(&hl[b], 1);
            int pos = bl[b] + rank;
            if (pos < (b + 1) * cap) {          // overflow guard (P ~ 1e-12)
                int idx = et[e] * N + ei[e];
                float iv = 1.0f / fmaxf(pl[e], EPSF);
                ep[pos] = make_uint2((unsigned)idx | ((unsigned)(dst & 63) << 20),
                                     __float_as_uint(iv));
            }
        }
    }
}

// ---------------- sortb: counting-sort bucket into node order ------------------
__global__ __launch_bounds__(256) void k_sortb(
    const uint2* __restrict__ ep, const int* __restrict__ cursor,
    uint2* __restrict__ ep2, int* __restrict__ rp, int B, int cap)
{
    __shared__ int hist[64];
    __shared__ int off[64];
    const int b = blockIdx.x, tid = threadIdx.x;
    const int beg = b * cap;
    int cnt = cursor[b] - beg;
    if (cnt > cap) cnt = cap;
    const int end = beg + cnt;
    if (tid < 64) hist[tid] = 0;
    __syncthreads();
    for (int p = beg + tid; p < end; p += 256)
        atomicAdd(&hist[(ep[p].x >> 20) & 63u], 1);
    __syncthreads();
    if (tid == 0) {
        int run = 0;
        #pragma unroll
        for (int i = 0; i < 64; ++i) { off[i] = run; run += hist[i]; }
    }
    __syncthreads();
    if (tid < 64) {
        rp[b * 65 + tid] = beg + off[tid];
        hist[tid] = 0;                    // reuse as rank cursor
    }
    if (tid == 64) rp[b * 65 + 64] = end;
    __syncthreads();
    for (int p = beg + tid; p < end; p += 256) {
        uint2 m = ep[p];
        int d = (m.x >> 20) & 63u;
        int rank = atomicAdd(&hist[d], 1);
        ep2[beg + off[d] + rank] = make_uint2(m.x & 0xFFFFFu, m.y);
    }
}

// ---------------- MFMA transform: Y[r][n][o] bf16 = x[n][:] @ W[r] -------------
__global__ __launch_bounds__(256) void k_transform_mfma(
    const float* __restrict__ x, const ushort_t* __restrict__ Wb,
    ushort_t* __restrict__ Y, int N)
{
    const int lane = threadIdx.x & 63;
    const int m0 = (blockIdx.x * 4 + (threadIdx.x >> 6)) * 16;
    if (m0 >= N) return;
    const int quad = lane >> 4, c = lane & 15;

    int node = m0 + c; if (node >= N) node = N - 1;
    const float* xr = x + (size_t)node * DD + quad * 8;
    float4 xa = *(const float4*)xr;
    float4 xb = *(const float4*)(xr + 4);
    float4 xc = *(const float4*)(xr + 32);
    float4 xd = *(const float4*)(xr + 36);
    F8 a0, a1;
    { uint2 p = pk4(xa), q = pk4(xb); a0.u = make_uint4(p.x, p.y, q.x, q.y); }
    { uint2 p = pk4(xc), q = pk4(xd); a1.u = make_uint4(p.x, p.y, q.x, q.y); }

    const uint4* wbp = (const uint4*)Wb + lane;
    const bool full = (m0 + 16 <= N);

    for (int r = 0; r < RR; ++r) {
        ushort_t* yr = Y + ((size_t)r * N + m0) * DD + c;
        #pragma unroll
        for (int ot = 0; ot < 4; ++ot) {
            F8 b0, b1;
            b0.u = wbp[(size_t)(r * 8 + ot) * 64];
            b1.u = wbp[(size_t)(r * 8 + 4 + ot) * 64];
            f32x4 acc = {0.f, 0.f, 0.f, 0.f};
            acc = __builtin_amdgcn_mfma_f32_16x16x32_bf16(a0.v, b0.v, acc, 0, 0, 0);
            acc = __builtin_amdgcn_mfma_f32_16x16x32_bf16(a1.v, b1.v, acc, 0, 0, 0);
            ushort_t* yp = yr + (ot << 4);
            if (full) {
                #pragma unroll
                for (int g = 0; g < 4; ++g)
                    yp[(size_t)(quad * 4 + g) * DD] = (ushort_t)f2bf(acc[g]);
            } else {
                #pragma unroll
                for (int g = 0; g < 4; ++g)
                    if (m0 + quad * 4 + g < N)
                        yp[(size_t)(quad * 4 + g) * DD] = (ushort_t)f2bf(acc[g]);
            }
        }
    }
}

// ---------------- aggregate: quarter-wave (16 lanes) per node ------------------
// Each lane owns outputs 4l..4l+3; per edge: uint2 gather (8B/lane), no reduce.
__global__ __launch_bounds__(256) void k_aggregate(
    const ushort_t* __restrict__ Y, const int* __restrict__ rp,
    const uint2* __restrict__ ep,
    const float* __restrict__ bias, float* __restrict__ out, int N)
{
    const int n = blockIdx.x * 16 + (threadIdx.x >> 4);
    const int l = threadIdx.x & 15;
    if (n >= N) return;
    const int b = n >> 6, i = n & 63;
    const int beg = rp[b * 65 + i], end = rp[b * 65 + i + 1];

    float a0 = 0.f, a1 = 0.f, a2 = 0.f, a3 = 0.f;
    for (int p0 = beg; p0 < end; p0 += 16) {
        int cnt = end - p0; if (cnt > 16) cnt = 16;
        unsigned pk = 0, ivb = 0;
        if (l < cnt) { uint2 m = ep[p0 + l]; pk = m.x; ivb = m.y; }
        for (int jj = 0; jj < cnt; jj += 8) {
            uint2 v[8]; float ivv[8];
            #pragma unroll
            for (int q = 0; q < 8; ++q) {
                int t = (jj + q) & 15;
                unsigned pkj = (unsigned)__shfl((int)pk, t, 16);
                float iv = __uint_as_float((unsigned)__shfl((int)ivb, t, 16));
                ivv[q] = (jj + q < cnt) ? iv : 0.f;
                v[q] = *(const uint2*)(Y + (size_t)pkj * DD + 4 * l);
            }
            #pragma unroll
            for (int q = 0; q < 8; ++q) {
                a0 = fmaf(bf_lo(v[q].x), ivv[q], a0);
                a1 = fmaf(bf_hi(v[q].x), ivv[q], a1);
                a2 = fmaf(bf_lo(v[q].y), ivv[q], a2);
                a3 = fmaf(bf_hi(v[q].y), ivv[q], a3);
            }
        }
    }
    float4 bb = *(const float4*)(bias + 4 * l);
    float4 o;
    o.x = fmaxf(a0 + bb.x, 0.f);
    o.y = fmaxf(a1 + bb.y, 0.f);
    o.z = fmaxf(a2 + bb.z, 0.f);
    o.w = fmaxf(a3 + bb.w, 0.f);
    *(float4*)(out + (size_t)n * DD + 4 * l) = o;
}

// ---------------- fallback (chunked, atomic) -----------------------------------
__global__ __launch_bounds__(256) void k_transform(
    const float* __restrict__ x, const float* __restrict__ W,
    ushort_t* __restrict__ Y, int N, int r_base, int r_cnt, int yr_off)
{
    __shared__ float xt[DD * 128];
    __shared__ float ws[DD * DD];
    const int n0 = blockIdx.x * 128;
    const int tid = threadIdx.x;

    #pragma unroll
    for (int c = 0; c < 8; ++c) {
        int idx = c * 256 + tid;
        int n  = idx >> 4;
        int i4 = (idx & 15) << 2;
        int gn = n0 + n;
        float4 v = make_float4(0.f, 0.f, 0.f, 0.f);
        if (gn < N) v = ((const float4*)(x + (size_t)gn * DD))[idx & 15];
        int n4 = n >> 2, nr = n & 3;
        float vv[4] = {v.x, v.y, v.z, v.w};
        #pragma unroll
        for (int k = 0; k < 4; ++k) {
            int i = i4 + k;
            int swz = (i >> 2) & 7;
            xt[i * 128 + (((n4 ^ swz) << 2) | nr)] = vv[k];
        }
    }

    const int j  = tid & 15;
    const int nq = tid >> 4;

    for (int rr = 0; rr < r_cnt; ++rr) {
        const int r = r_base + blockIdx.y * r_cnt + rr;
        __syncthreads();
        {
            const float4* Wv = (const float4*)(W + (size_t)r * DD * DD);
            float4* wv = (float4*)ws;
            #pragma unroll
            for (int c = 0; c < 4; ++c) wv[c * 256 + tid] = Wv[c * 256 + tid];
        }
        __syncthreads();

        float4 acc[8];
        #pragma unroll
        for (int m = 0; m < 8; ++m) acc[m] = make_float4(0.f, 0.f, 0.f, 0.f);

        #pragma unroll 4
        for (int i = 0; i < DD; ++i) {
            const int swz = (i >> 2) & 7;
            const float4 wv = *(const float4*)&ws[i * DD + 4 * j];
            #pragma unroll
            for (int h = 0; h < 2; ++h) {
                const int col4 = (2 * nq + h) ^ swz;
                const float4 xv = *(const float4*)&xt[i * 128 + (col4 << 2)];
                fma4(acc[4 * h + 0], wv, xv.x);
                fma4(acc[4 * h + 1], wv, xv.y);
                fma4(acc[4 * h + 2], wv, xv.z);
                fma4(acc[4 * h + 3], wv, xv.w);
            }
        }

        const size_t ybase = (size_t)(r - yr_off) * N;
        #pragma unroll
        for (int m = 0; m < 8; ++m) {
            int node = n0 + 8 * nq + 4 * (m >> 2) + (m & 3);
            if (node < N)
                *(uint2*)(Y + (ybase + node) * DD + 4 * j) = pk4(acc[m]);
        }
    }
}

__global__ __launch_bounds__(256) void k_edges(
    const int* __restrict__ ei, const int* __restrict__ et,
    const float* __restrict__ pl, const ushort_t* __restrict__ Y,
    float* __restrict__ aggr, int N, int E, int Etot, int rel_filter)
{
    int sub = threadIdx.x >> 5;
    int lane = threadIdx.x & 31;
    int e = blockIdx.x * 8 + sub;
    if (e >= Etot) return;
    int rt = et[e];
    int yrel = rt;
    if (rel_filter >= 0) { if (rt != rel_filter) return; yrel = 0; }
    int src, dst;
    if (e < E) { src = ei[e]; dst = ei[E + e]; }
    else       { src = dst = e - E; }
    float inv = 1.0f / fmaxf(pl[e], EPSF);
    unsigned v = *(const unsigned*)(Y + ((size_t)yrel * N + src) * DD + 2 * lane);
    atomicAdd(&aggr[(size_t)dst * DD + 2 * lane],     bf_lo(v) * inv);
    atomicAdd(&aggr[(size_t)dst * DD + 2 * lane + 1], bf_hi(v) * inv);
}

__global__ __launch_bounds__(256) void k_bias_relu(
    const float* __restrict__ aggr, const float* __restrict__ bias,
    float* __restrict__ out, int N)
{
    int idx = blockIdx.x * 256 + threadIdx.x;
    if (idx >= N * (DD / 4)) return;
    float4 a = ((const float4*)aggr)[idx];
    int o4 = (idx & 15) * 4;
    a.x = fmaxf(a.x + bias[o4 + 0], 0.f);
    a.y = fmaxf(a.y + bias[o4 + 1], 0.f);
    a.z = fmaxf(a.z + bias[o4 + 2], 0.f);
    a.w = fmaxf(a.w + bias[o4 + 3], 0.f);
    ((float4*)out)[idx] = a;
}

__global__ __launch_bounds__(256) void k_zero(float* __restrict__ p, size_t n)
{
    size_t i = (size_t)blockIdx.x * 256 + threadIdx.x;
    size_t stride = (size_t)gridDim.x * 256;
    for (; i < n; i += stride) p[i] = 0.f;
}

extern "C" void kernel_launch(void* const* d_in, const int* in_sizes, int n_in,
                              void* d_out, int out_size, void* d_ws, size_t ws_size,
                              hipStream_t stream)
{
    const float* x  = (const float*)d_in[0];
    const int*   ei = (const int*)d_in[1];
    const int*   et = (const int*)d_in[2];
    const float* pl = (const float*)d_in[3];
    const float* W1 = (const float*)d_in[4];
    const float* b1 = (const float*)d_in[5];
    const float* W2 = (const float*)d_in[6];
    const float* b2 = (const float*)d_in[7];
    float* out = (float*)d_out;

    const int N = in_sizes[0] / DD;
    const int E = in_sizes[1] / 2;
    const size_t ndf = (size_t)N * DD;
    const size_t wb_elems = (size_t)RR * 2 * 4 * 64 * 8;   // 65536 ushorts
    const int B = (N + 63) / 64;                            // 64-node buckets

    int avg = (E + B - 1) / B;
    int cap = avg + 8 * (int)sqrtf((float)avg) + 128;       // + self-loop head
    cap = (cap + 3) & ~3;

    char* wsb = (char*)d_ws;
    ushort_t* Y   = (ushort_t*)wsb;                          // RR*ndf bf16
    float* aggr1  = (float*)(wsb + (size_t)RR * ndf * 2);    // ndf fp32 (hidden)
    ushort_t* Wb1 = (ushort_t*)((char*)aggr1 + ndf * 4);     // 128 KB
    ushort_t* Wb2 = Wb1 + wb_elems;                          // 128 KB
    uint2* ep     = (uint2*)(Wb2 + wb_elems);                // B*cap
    uint2* ep2    = ep + (size_t)B * cap;                    // B*cap
    int* cursor   = (int*)(ep2 + (size_t)B * cap);           // B
    int* rp       = cursor + B;                              // B*65

    const size_t need_main = (size_t)RR * ndf * 2 + ndf * 4 + wb_elems * 4 +
        (size_t)B * cap * 16 + ((size_t)B * 66) * 4;
    const bool main_ok = (ws_size >= need_main) && (N <= 65535) && (B <= 1024);

    if (main_ok) {
        const int gBin = (E + BINCH - 1) / BINCH;
        k_prep<<<(16384 + B + N + 255) / 256, 256, 0, stream>>>(
            W1, W2, Wb1, Wb2, cursor, ep, et, pl, B, cap, N, E);
        k_bin<<<gBin, 256, 0, stream>>>(ei, et, pl, cursor, ep, E, B, N, cap);
        k_sortb<<<B, 256, 0, stream>>>(ep, cursor, ep2, rp, B, cap);

        const int gT = (N + 63) / 64;
        const int gA = (N + 15) / 16;
        for (int layer = 0; layer < 2; ++layer) {
            const float* xin   = layer ? aggr1 : x;
            const ushort_t* Wb = layer ? Wb2 : Wb1;
            const float* bias  = layer ? b2 : b1;
            float* dest        = layer ? out : aggr1;
            k_transform_mfma<<<gT, 256, 0, stream>>>(xin, Wb, Y, N);
            k_aggregate<<<gA, 256, 0, stream>>>(Y, rp, ep2, bias, dest, N);
        }
        return;
    }

    // chunked fallback: Yc = ndf bf16, aggr = ndf fp32
    ushort_t* Yc = (ushort_t*)wsb;
    float* ag    = (float*)(wsb + ndf * 2);
    const int gx     = (N + 127) / 128;
    const int gEdgeT = (E + N + 7) / 8;
    const int gQuad  = (N * (DD / 4) + 255) / 256;
    float* hid = ag;

    for (int layer = 0; layer < 2; ++layer) {
        const float* xin  = layer ? hid : x;
        const float* W    = layer ? W2 : W1;
        const float* bias = layer ? b2 : b1;
        float* aggr       = layer ? out : ag;
        k_zero<<<1024, 256, 0, stream>>>(aggr, ndf);
        for (int r = 0; r < RR; ++r) {
            k_transform<<<dim3(gx, 1), 256, 0, stream>>>(xin, W, Yc, N, r, 1, r);
            k_edges<<<gEdgeT, 256, 0, stream>>>(ei, et, pl, Yc, aggr, N, E, E + N, r);
        }
        k_bias_relu<<<gQuad, 256, 0, stream>>>(aggr, bias, layer ? out : hid, N);
    }
}

// Round 10
// 219.286 us; speedup vs baseline: 1.0389x; 1.0389x over previous
//
#include <hip/hip_runtime.h>

#define DD 64
#define RR 16
#define EPSF 1e-9f
#define BINCH 4096        // edges per bin block (64-node buckets)

typedef unsigned short ushort_t;
typedef __bf16 bf16x8 __attribute__((ext_vector_type(8)));
typedef float f32x4 __attribute__((ext_vector_type(4)));
union F8 { uint4 u; bf16x8 v; };

__device__ __forceinline__ void fma4(float4& a, const float4& w, float s) {
    a.x = fmaf(w.x, s, a.x); a.y = fmaf(w.y, s, a.y);
    a.z = fmaf(w.z, s, a.z); a.w = fmaf(w.w, s, a.w);
}
__device__ __forceinline__ unsigned f2bf(float f) {
    unsigned u = __float_as_uint(f);
    return (u + 0x7FFFu + ((u >> 16) & 1u)) >> 16;   // RNE
}
__device__ __forceinline__ uint2 pk4(float4 v) {
    return make_uint2(f2bf(v.x) | (f2bf(v.y) << 16),
                      f2bf(v.z) | (f2bf(v.w) << 16));
}
__device__ __forceinline__ float bf_lo(unsigned u) { return __uint_as_float(u << 16); }
__device__ __forceinline__ float bf_hi(unsigned u) { return __uint_as_float(u & 0xFFFF0000u); }

// ---------------- prep: pack W1+W2, init cursors, emit self-loop records -------
__device__ __forceinline__ void packW_one(
    const float* __restrict__ W, ushort_t* __restrict__ Wb, int t)
{
    int lane = t & 63;
    int ot = (t >> 6) & 3;
    int kb = (t >> 8) & 1;
    int r  = t >> 9;
    int o  = ot * 16 + (lane & 15);
    int k0 = kb * 32 + (lane >> 4) * 8;
    const float* w = W + ((size_t)r * DD + k0) * DD + o;
    unsigned d[4];
    #pragma unroll
    for (int p = 0; p < 4; ++p)
        d[p] = f2bf(w[(2 * p) * DD]) | (f2bf(w[(2 * p + 1) * DD]) << 16);
    ((uint4*)Wb)[t] = make_uint4(d[0], d[1], d[2], d[3]);
}

__global__ __launch_bounds__(256) void k_prep(
    const float* __restrict__ W1, const float* __restrict__ W2,
    ushort_t* __restrict__ Wb1, ushort_t* __restrict__ Wb2,
    int* __restrict__ cursor, uint2* __restrict__ ep,
    const int* __restrict__ et, const float* __restrict__ pl,
    int B, int cap, int N, int E)
{
    int tid = blockIdx.x * 256 + threadIdx.x;
    if (tid < 8192)            packW_one(W1, Wb1, tid);
    else if (tid < 16384)      packW_one(W2, Wb2, tid - 8192);
    else if (tid < 16384 + B) {
        int b = tid - 16384;
        int nb = N - b * 64; if (nb > 64) nb = 64;
        cursor[b] = b * cap + nb;            // self records occupy the head
    } else if (tid < 16384 + B + N) {
        int n = tid - 16384 - B;
        int b = n >> 6;
        int idx = et[E + n] * N + n;         // rt*N+n < 2^20
        float iv = 1.0f / fmaxf(pl[E + n], EPSF);
        ep[(size_t)b * cap + (n & 63)] = make_uint2(
            (unsigned)idx | ((unsigned)(n & 63) << 20), __float_as_uint(iv));
    }
}

// ---------------- bin: single global pass, LDS record cache --------------------
// rec = {(rt*N+src) | (dst&63)<<20, iv};  bucket b segment = [b*cap, (b+1)*cap)
__global__ __launch_bounds__(256) void k_bin(
    const int* __restrict__ ei, const int* __restrict__ et,
    const float* __restrict__ pl, int* __restrict__ cursor,
    uint2* __restrict__ ep, int E, int B, int N, int cap)
{
    __shared__ int hl[1024];
    __shared__ int bl[1024];
    __shared__ unsigned lkey[BINCH];
    __shared__ unsigned ldst[BINCH];
    __shared__ float    liv[BINCH];
    for (int i = threadIdx.x; i < B; i += 256) hl[i] = 0;
    __syncthreads();
    const int e0 = blockIdx.x * BINCH;
    #pragma unroll 4
    for (int k = 0; k < BINCH / 256; ++k) {
        int i = k * 256 + threadIdx.x;
        int e = e0 + i;
        if (e < E) {
            int dst = ei[E + e];
            atomicAdd(&hl[dst >> 6], 1);
            lkey[i] = (unsigned)(et[e] * N + ei[e]);
            ldst[i] = (unsigned)dst;
            liv[i]  = 1.0f / fmaxf(pl[e], EPSF);
        }
    }
    __syncthreads();
    for (int i = threadIdx.x; i < B; i += 256) {
        int c = hl[i];
        bl[i] = c ? atomicAdd(&cursor[i], c) : 0;
        hl[i] = 0;
    }
    __syncthreads();
    #pragma unroll 2
    for (int k = 0; k < BINCH / 256; ++k) {
        int i = k * 256 + threadIdx.x;
        int e = e0 + i;
        if (e < E) {
            unsigned dst = ldst[i];
            int b = dst >> 6;
            int rank = atomicAdd(&hl[b], 1);
            int pos = bl[b] + rank;
            if (pos < (b + 1) * cap)            // overflow guard (P ~ 1e-12)
                ep[pos] = make_uint2(lkey[i] | ((dst & 63u) << 20),
                                     __float_as_uint(liv[i]));
        }
    }
}

// ---------------- sortb: counting-sort bucket into node order ------------------
__global__ __launch_bounds__(256) void k_sortb(
    const uint2* __restrict__ ep, const int* __restrict__ cursor,
    uint2* __restrict__ ep2, int* __restrict__ rp, int B, int cap)
{
    __shared__ int hist[64];
    __shared__ int off[64];
    const int b = blockIdx.x, tid = threadIdx.x;
    const int beg = b * cap;
    int cnt = cursor[b] - beg;
    if (cnt > cap) cnt = cap;
    const int end = beg + cnt;
    if (tid < 64) hist[tid] = 0;
    __syncthreads();
    for (int p = beg + tid; p < end; p += 256)
        atomicAdd(&hist[(ep[p].x >> 20) & 63u], 1);
    __syncthreads();
    if (tid < 64) {                       // wave shfl-scan (exclusive)
        int v = hist[tid], s = v;
        #pragma unroll
        for (int o = 1; o < 64; o <<= 1) {
            int t = __shfl_up(s, o, 64);
            if (tid >= o) s += t;
        }
        off[tid] = s - v;
        rp[b * 65 + tid] = beg + s - v;
        hist[tid] = 0;                    // reuse as rank cursor
    }
    if (tid == 64) rp[b * 65 + 64] = end;
    __syncthreads();
    for (int p = beg + tid; p < end; p += 256) {
        uint2 m = ep[p];
        int d = (m.x >> 20) & 63u;
        int rank = atomicAdd(&hist[d], 1);
        ep2[beg + off[d] + rank] = make_uint2(m.x & 0xFFFFFu, m.y);
    }
}

// ---------------- MFMA transform: Y[r][n][o] bf16 = x[n][:] @ W[r] -------------
__global__ __launch_bounds__(256) void k_transform_mfma(
    const float* __restrict__ x, const ushort_t* __restrict__ Wb,
    ushort_t* __restrict__ Y, int N)
{
    const int lane = threadIdx.x & 63;
    const int m0 = (blockIdx.x * 4 + (threadIdx.x >> 6)) * 16;
    if (m0 >= N) return;
    const int quad = lane >> 4, c = lane & 15;

    int node = m0 + c; if (node >= N) node = N - 1;
    const float* xr = x + (size_t)node * DD + quad * 8;
    float4 xa = *(const float4*)xr;
    float4 xb = *(const float4*)(xr + 4);
    float4 xc = *(const float4*)(xr + 32);
    float4 xd = *(const float4*)(xr + 36);
    F8 a0, a1;
    { uint2 p = pk4(xa), q = pk4(xb); a0.u = make_uint4(p.x, p.y, q.x, q.y); }
    { uint2 p = pk4(xc), q = pk4(xd); a1.u = make_uint4(p.x, p.y, q.x, q.y); }

    const uint4* wbp = (const uint4*)Wb + lane;
    const bool full = (m0 + 16 <= N);

    for (int r = 0; r < RR; ++r) {
        ushort_t* yr = Y + ((size_t)r * N + m0) * DD + c;
        #pragma unroll
        for (int ot = 0; ot < 4; ++ot) {
            F8 b0, b1;
            b0.u = wbp[(size_t)(r * 8 + ot) * 64];
            b1.u = wbp[(size_t)(r * 8 + 4 + ot) * 64];
            f32x4 acc = {0.f, 0.f, 0.f, 0.f};
            acc = __builtin_amdgcn_mfma_f32_16x16x32_bf16(a0.v, b0.v, acc, 0, 0, 0);
            acc = __builtin_amdgcn_mfma_f32_16x16x32_bf16(a1.v, b1.v, acc, 0, 0, 0);
            ushort_t* yp = yr + (ot << 4);
            if (full) {
                #pragma unroll
                for (int g = 0; g < 4; ++g)
                    yp[(size_t)(quad * 4 + g) * DD] = (ushort_t)f2bf(acc[g]);
            } else {
                #pragma unroll
                for (int g = 0; g < 4; ++g)
                    if (m0 + quad * 4 + g < N)
                        yp[(size_t)(quad * 4 + g) * DD] = (ushort_t)f2bf(acc[g]);
            }
        }
    }
}

// ---------------- aggregate: half-wave (32 lanes) per node, 8-deep pipeline ----
__global__ __launch_bounds__(256) void k_aggregate(
    const ushort_t* __restrict__ Y, const int* __restrict__ rp,
    const uint2* __restrict__ ep,
    const float* __restrict__ bias, float* __restrict__ out, int N)
{
    const int n = blockIdx.x * 8 + (threadIdx.x >> 5);
    const int lane = threadIdx.x & 31;
    if (n >= N) return;
    const int b = n >> 6, i = n & 63;
    const int beg = rp[b * 65 + i], end = rp[b * 65 + i + 1];

    float accx = 0.f, accy = 0.f;
    for (int p0 = beg; p0 < end; p0 += 32) {
        int cnt = end - p0; if (cnt > 32) cnt = 32;
        unsigned pk = 0, ivb = 0;
        if (lane < cnt) { uint2 m = ep[p0 + lane]; pk = m.x; ivb = m.y; }
        for (int jj = 0; jj < cnt; jj += 8) {
            unsigned v[8]; float ivv[8];
            #pragma unroll
            for (int q = 0; q < 8; ++q) {
                int t = (jj + q) & 31;
                unsigned pkj = (unsigned)__shfl((int)pk, t, 32);
                float iv = __uint_as_float((unsigned)__shfl((int)ivb, t, 32));
                ivv[q] = (jj + q < cnt) ? iv : 0.f;
                v[q] = *(const unsigned*)(Y + (size_t)(pkj & 0xFFFFFu) * DD + 2 * lane);
            }
            #pragma unroll
            for (int q = 0; q < 8; ++q) {
                accx = fmaf(bf_lo(v[q]), ivv[q], accx);
                accy = fmaf(bf_hi(v[q]), ivv[q], accy);
            }
        }
    }
    float2 bb = *(const float2*)(bias + 2 * lane);
    float2 o;
    o.x = fmaxf(accx + bb.x, 0.f);
    o.y = fmaxf(accy + bb.y, 0.f);
    *(float2*)(out + (size_t)n * DD + 2 * lane) = o;
}

// ---------------- fallback (chunked, atomic) -----------------------------------
__global__ __launch_bounds__(256) void k_transform(
    const float* __restrict__ x, const float* __restrict__ W,
    ushort_t* __restrict__ Y, int N, int r_base, int r_cnt, int yr_off)
{
    __shared__ float xt[DD * 128];
    __shared__ float ws[DD * DD];
    const int n0 = blockIdx.x * 128;
    const int tid = threadIdx.x;

    #pragma unroll
    for (int c = 0; c < 8; ++c) {
        int idx = c * 256 + tid;
        int n  = idx >> 4;
        int i4 = (idx & 15) << 2;
        int gn = n0 + n;
        float4 v = make_float4(0.f, 0.f, 0.f, 0.f);
        if (gn < N) v = ((const float4*)(x + (size_t)gn * DD))[idx & 15];
        int n4 = n >> 2, nr = n & 3;
        float vv[4] = {v.x, v.y, v.z, v.w};
        #pragma unroll
        for (int k = 0; k < 4; ++k) {
            int i = i4 + k;
            int swz = (i >> 2) & 7;
            xt[i * 128 + (((n4 ^ swz) << 2) | nr)] = vv[k];
        }
    }

    const int j  = tid & 15;
    const int nq = tid >> 4;

    for (int rr = 0; rr < r_cnt; ++rr) {
        const int r = r_base + blockIdx.y * r_cnt + rr;
        __syncthreads();
        {
            const float4* Wv = (const float4*)(W + (size_t)r * DD * DD);
            float4* wv = (float4*)ws;
            #pragma unroll
            for (int c = 0; c < 4; ++c) wv[c * 256 + tid] = Wv[c * 256 + tid];
        }
        __syncthreads();

        float4 acc[8];
        #pragma unroll
        for (int m = 0; m < 8; ++m) acc[m] = make_float4(0.f, 0.f, 0.f, 0.f);

        #pragma unroll 4
        for (int i = 0; i < DD; ++i) {
            const int swz = (i >> 2) & 7;
            const float4 wv = *(const float4*)&ws[i * DD + 4 * j];
            #pragma unroll
            for (int h = 0; h < 2; ++h) {
                const int col4 = (2 * nq + h) ^ swz;
                const float4 xv = *(const float4*)&xt[i * 128 + (col4 << 2)];
                fma4(acc[4 * h + 0], wv, xv.x);
                fma4(acc[4 * h + 1], wv, xv.y);
                fma4(acc[4 * h + 2], wv, xv.z);
                fma4(acc[4 * h + 3], wv, xv.w);
            }
        }

        const size_t ybase = (size_t)(r - yr_off) * N;
        #pragma unroll
        for (int m = 0; m < 8; ++m) {
            int node = n0 + 8 * nq + 4 * (m >> 2) + (m & 3);
            if (node < N)
                *(uint2*)(Y + (ybase + node) * DD + 4 * j) = pk4(acc[m]);
        }
    }
}

__global__ __launch_bounds__(256) void k_edges(
    const int* __restrict__ ei, const int* __restrict__ et,
    const float* __restrict__ pl, const ushort_t* __restrict__ Y,
    float* __restrict__ aggr, int N, int E, int Etot, int rel_filter)
{
    int sub = threadIdx.x >> 5;
    int lane = threadIdx.x & 31;
    int e = blockIdx.x * 8 + sub;
    if (e >= Etot) return;
    int rt = et[e];
    int yrel = rt;
    if (rel_filter >= 0) { if (rt != rel_filter) return; yrel = 0; }
    int src, dst;
    if (e < E) { src = ei[e]; dst = ei[E + e]; }
    else       { src = dst = e - E; }
    float inv = 1.0f / fmaxf(pl[e], EPSF);
    unsigned v = *(const unsigned*)(Y + ((size_t)yrel * N + src) * DD + 2 * lane);
    atomicAdd(&aggr[(size_t)dst * DD + 2 * lane],     bf_lo(v) * inv);
    atomicAdd(&aggr[(size_t)dst * DD + 2 * lane + 1], bf_hi(v) * inv);
}

__global__ __launch_bounds__(256) void k_bias_relu(
    const float* __restrict__ aggr, const float* __restrict__ bias,
    float* __restrict__ out, int N)
{
    int idx = blockIdx.x * 256 + threadIdx.x;
    if (idx >= N * (DD / 4)) return;
    float4 a = ((const float4*)aggr)[idx];
    int o4 = (idx & 15) * 4;
    a.x = fmaxf(a.x + bias[o4 + 0], 0.f);
    a.y = fmaxf(a.y + bias[o4 + 1], 0.f);
    a.z = fmaxf(a.z + bias[o4 + 2], 0.f);
    a.w = fmaxf(a.w + bias[o4 + 3], 0.f);
    ((float4*)out)[idx] = a;
}

__global__ __launch_bounds__(256) void k_zero(float* __restrict__ p, size_t n)
{
    size_t i = (size_t)blockIdx.x * 256 + threadIdx.x;
    size_t stride = (size_t)gridDim.x * 256;
    for (; i < n; i += stride) p[i] = 0.f;
}

extern "C" void kernel_launch(void* const* d_in, const int* in_sizes, int n_in,
                              void* d_out, int out_size, void* d_ws, size_t ws_size,
                              hipStream_t stream)
{
    const float* x  = (const float*)d_in[0];
    const int*   ei = (const int*)d_in[1];
    const int*   et = (const int*)d_in[2];
    const float* pl = (const float*)d_in[3];
    const float* W1 = (const float*)d_in[4];
    const float* b1 = (const float*)d_in[5];
    const float* W2 = (const float*)d_in[6];
    const float* b2 = (const float*)d_in[7];
    float* out = (float*)d_out;

    const int N = in_sizes[0] / DD;
    const int E = in_sizes[1] / 2;
    const size_t ndf = (size_t)N * DD;
    const size_t wb_elems = (size_t)RR * 2 * 4 * 64 * 8;   // 65536 ushorts
    const int B = (N + 63) / 64;                            // 64-node buckets

    int avg = (E + B - 1) / B;
    int cap = avg + 8 * (int)sqrtf((float)avg) + 128;       // + self-loop head
    cap = (cap + 3) & ~3;

    char* wsb = (char*)d_ws;
    ushort_t* Y   = (ushort_t*)wsb;                          // RR*ndf bf16
    float* aggr1  = (float*)(wsb + (size_t)RR * ndf * 2);    // ndf fp32 (hidden)
    ushort_t* Wb1 = (ushort_t*)((char*)aggr1 + ndf * 4);     // 128 KB
    ushort_t* Wb2 = Wb1 + wb_elems;                          // 128 KB
    uint2* ep     = (uint2*)(Wb2 + wb_elems);                // B*cap
    uint2* ep2    = ep + (size_t)B * cap;                    // B*cap
    int* cursor   = (int*)(ep2 + (size_t)B * cap);           // B
    int* rp       = cursor + B;                              // B*65

    const size_t need_main = (size_t)RR * ndf * 2 + ndf * 4 + wb_elems * 4 +
        (size_t)B * cap * 16 + ((size_t)B * 66) * 4;
    const bool main_ok = (ws_size >= need_main) && (N <= 65535) && (B <= 1024);

    if (main_ok) {
        const int gBin = (E + BINCH - 1) / BINCH;
        k_prep<<<(16384 + B + N + 255) / 256, 256, 0, stream>>>(
            W1, W2, Wb1, Wb2, cursor, ep, et, pl, B, cap, N, E);
        k_bin<<<gBin, 256, 0, stream>>>(ei, et, pl, cursor, ep, E, B, N, cap);
        k_sortb<<<B, 256, 0, stream>>>(ep, cursor, ep2, rp, B, cap);

        const int gT = (N + 63) / 64;
        const int gA = (N + 7) / 8;
        for (int layer = 0; layer < 2; ++layer) {
            const float* xin   = layer ? aggr1 : x;
            const ushort_t* Wb = layer ? Wb2 : Wb1;
            const float* bias  = layer ? b2 : b1;
            float* dest        = layer ? out : aggr1;
            k_transform_mfma<<<gT, 256, 0, stream>>>(xin, Wb, Y, N);
            k_aggregate<<<gA, 256, 0, stream>>>(Y, rp, ep2, bias, dest, N);
        }
        return;
    }

    // chunked fallback: Yc = ndf bf16, aggr = ndf fp32
    ushort_t* Yc = (ushort_t*)wsb;
    float* ag    = (float*)(wsb + ndf * 2);
    const int gx     = (N + 127) / 128;
    const int gEdgeT = (E + N + 7) / 8;
    const int gQuad  = (N * (DD / 4) + 255) / 256;
    float* hid = ag;

    for (int layer = 0; layer < 2; ++layer) {
        const float* xin  = layer ? hid : x;
        const float* W    = layer ? W2 : W1;
        const float* bias = layer ? b2 : b1;
        float* aggr       = layer ? out : ag;
        k_zero<<<1024, 256, 0, stream>>>(aggr, ndf);
        for (int r = 0; r < RR; ++r) {
            k_transform<<<dim3(gx, 1), 256, 0, stream>>>(xin, W, Yc, N, r, 1, r);
            k_edges<<<gEdgeT, 256, 0, stream>>>(ei, et, pl, Yc, aggr, N, E, E + N, r);
        }
        k_bias_relu<<<gQuad, 256, 0, stream>>>(aggr, bias, layer ? out : hid, N);
    }
}

// Round 11
// 210.858 us; speedup vs baseline: 1.0805x; 1.0400x over previous
//
#include <hip/hip_runtime.h>

#define DD 64
#define RR 16
#define EPSF 1e-9f
#define BINCH 4096        // edges per bin block (64-node buckets)

typedef unsigned short ushort_t;
typedef __bf16 bf16x8 __attribute__((ext_vector_type(8)));
typedef float f32x4 __attribute__((ext_vector_type(4)));
union F8 { uint4 u; bf16x8 v; };

__device__ __forceinline__ void fma4(float4& a, const float4& w, float s) {
    a.x = fmaf(w.x, s, a.x); a.y = fmaf(w.y, s, a.y);
    a.z = fmaf(w.z, s, a.z); a.w = fmaf(w.w, s, a.w);
}
__device__ __forceinline__ unsigned f2bf(float f) {
    unsigned u = __float_as_uint(f);
    return (u + 0x7FFFu + ((u >> 16) & 1u)) >> 16;   // RNE
}
__device__ __forceinline__ uint2 pk4(float4 v) {
    return make_uint2(f2bf(v.x) | (f2bf(v.y) << 16),
                      f2bf(v.z) | (f2bf(v.w) << 16));
}
__device__ __forceinline__ float bf_lo(unsigned u) { return __uint_as_float(u << 16); }
__device__ __forceinline__ float bf_hi(unsigned u) { return __uint_as_float(u & 0xFFFF0000u); }

// ---------------- prep: pack W1+W2, init cursors, emit self-loop records -------
__device__ __forceinline__ void packW_one(
    const float* __restrict__ W, ushort_t* __restrict__ Wb, int t)
{
    int lane = t & 63;
    int ot = (t >> 6) & 3;
    int kb = (t >> 8) & 1;
    int r  = t >> 9;
    int o  = ot * 16 + (lane & 15);
    int k0 = kb * 32 + (lane >> 4) * 8;
    const float* w = W + ((size_t)r * DD + k0) * DD + o;
    unsigned d[4];
    #pragma unroll
    for (int p = 0; p < 4; ++p)
        d[p] = f2bf(w[(2 * p) * DD]) | (f2bf(w[(2 * p + 1) * DD]) << 16);
    ((uint4*)Wb)[t] = make_uint4(d[0], d[1], d[2], d[3]);
}

__global__ __launch_bounds__(256) void k_prep(
    const float* __restrict__ W1, const float* __restrict__ W2,
    ushort_t* __restrict__ Wb1, ushort_t* __restrict__ Wb2,
    int* __restrict__ cursor, uint2* __restrict__ ep,
    const int* __restrict__ et, const float* __restrict__ pl,
    int B, int cap, int N, int E)
{
    int tid = blockIdx.x * 256 + threadIdx.x;
    if (tid < 8192)            packW_one(W1, Wb1, tid);
    else if (tid < 16384)      packW_one(W2, Wb2, tid - 8192);
    else if (tid < 16384 + B) {
        int b = tid - 16384;
        int nb = N - b * 64; if (nb > 64) nb = 64;
        cursor[b] = b * cap + nb;            // self records occupy the head
    } else if (tid < 16384 + B + N) {
        int n = tid - 16384 - B;
        int b = n >> 6;
        int idx = et[E + n] * N + n;         // rt*N+n < 2^20
        float iv = 1.0f / fmaxf(pl[E + n], EPSF);
        ep[(size_t)b * cap + (n & 63)] = make_uint2(
            (unsigned)idx | ((unsigned)(n & 63) << 20), __float_as_uint(iv));
    }
}

// ---------------- bin: single global pass, LDS record cache --------------------
// rec = {(rt*N+src) | (dst&63)<<20, iv};  bucket b segment = [b*cap, (b+1)*cap)
__global__ __launch_bounds__(256) void k_bin(
    const int* __restrict__ ei, const int* __restrict__ et,
    const float* __restrict__ pl, int* __restrict__ cursor,
    uint2* __restrict__ ep, int E, int B, int N, int cap)
{
    __shared__ int hl[1024];
    __shared__ int bl[1024];
    __shared__ unsigned lkey[BINCH];
    __shared__ unsigned ldst[BINCH];
    __shared__ float    liv[BINCH];
    for (int i = threadIdx.x; i < B; i += 256) hl[i] = 0;
    __syncthreads();
    const int e0 = blockIdx.x * BINCH;
    #pragma unroll 4
    for (int k = 0; k < BINCH / 256; ++k) {
        int i = k * 256 + threadIdx.x;
        int e = e0 + i;
        if (e < E) {
            int dst = ei[E + e];
            atomicAdd(&hl[dst >> 6], 1);
            lkey[i] = (unsigned)(et[e] * N + ei[e]);
            ldst[i] = (unsigned)dst;
            liv[i]  = 1.0f / fmaxf(pl[e], EPSF);
        }
    }
    __syncthreads();
    for (int i = threadIdx.x; i < B; i += 256) {
        int c = hl[i];
        bl[i] = c ? atomicAdd(&cursor[i], c) : 0;
        hl[i] = 0;
    }
    __syncthreads();
    #pragma unroll 2
    for (int k = 0; k < BINCH / 256; ++k) {
        int i = k * 256 + threadIdx.x;
        int e = e0 + i;
        if (e < E) {
            unsigned dst = ldst[i];
            int b = dst >> 6;
            int rank = atomicAdd(&hl[b], 1);
            int pos = bl[b] + rank;
            if (pos < (b + 1) * cap)            // overflow guard (P ~ 1e-12)
                ep[pos] = make_uint2(lkey[i] | ((dst & 63u) << 20),
                                     __float_as_uint(liv[i]));
        }
    }
}

// ---------------- sortb: counting-sort bucket into node order ------------------
__global__ __launch_bounds__(256) void k_sortb(
    const uint2* __restrict__ ep, const int* __restrict__ cursor,
    uint2* __restrict__ ep2, int* __restrict__ rp, int B, int cap)
{
    __shared__ int hist[64];
    __shared__ int off[64];
    const int b = blockIdx.x, tid = threadIdx.x;
    const int beg = b * cap;
    int cnt = cursor[b] - beg;
    if (cnt > cap) cnt = cap;
    const int end = beg + cnt;
    if (tid < 64) hist[tid] = 0;
    __syncthreads();
    for (int p = beg + tid; p < end; p += 256)
        atomicAdd(&hist[(ep[p].x >> 20) & 63u], 1);
    __syncthreads();
    if (tid < 64) {                       // wave shfl-scan (exclusive)
        int v = hist[tid], s = v;
        #pragma unroll
        for (int o = 1; o < 64; o <<= 1) {
            int t = __shfl_up(s, o, 64);
            if (tid >= o) s += t;
        }
        off[tid] = s - v;
        rp[b * 65 + tid] = beg + s - v;
        hist[tid] = 0;                    // reuse as rank cursor
    }
    if (tid == 64) rp[b * 65 + 64] = end;
    __syncthreads();
    for (int p = beg + tid; p < end; p += 256) {
        uint2 m = ep[p];
        int d = (m.x >> 20) & 63u;
        int rank = atomicAdd(&hist[d], 1);
        ep2[beg + off[d] + rank] = make_uint2(m.x & 0xFFFFFu, m.y);
    }
}

// ---------------- MFMA transform: Y permuted-row layout ------------------------
// Y[row = r*N+n][o'] with o' = 4c + ot  (col = (o'&3)*16 + (o'>>2)).
// Each lane stores uint2 (4 bf16, one per ot) per row: 16 lanes x 8B = 128B/row.
__global__ __launch_bounds__(256) void k_transform_mfma(
    const float* __restrict__ x, const ushort_t* __restrict__ Wb,
    ushort_t* __restrict__ Y, int N)
{
    const int lane = threadIdx.x & 63;
    const int m0 = (blockIdx.x * 4 + (threadIdx.x >> 6)) * 16;
    if (m0 >= N) return;
    const int quad = lane >> 4, c = lane & 15;

    int node = m0 + c; if (node >= N) node = N - 1;
    const float* xr = x + (size_t)node * DD + quad * 8;
    float4 xa = *(const float4*)xr;
    float4 xb = *(const float4*)(xr + 4);
    float4 xc = *(const float4*)(xr + 32);
    float4 xd = *(const float4*)(xr + 36);
    F8 a0, a1;
    { uint2 p = pk4(xa), q = pk4(xb); a0.u = make_uint4(p.x, p.y, q.x, q.y); }
    { uint2 p = pk4(xc), q = pk4(xd); a1.u = make_uint4(p.x, p.y, q.x, q.y); }

    const uint4* wbp = (const uint4*)Wb + lane;
    const bool full = (m0 + 16 <= N);

    for (int r = 0; r < RR; ++r) {
        f32x4 accs[4];
        #pragma unroll
        for (int ot = 0; ot < 4; ++ot) {
            F8 b0, b1;
            b0.u = wbp[(size_t)(r * 8 + ot) * 64];
            b1.u = wbp[(size_t)(r * 8 + 4 + ot) * 64];
            f32x4 acc = {0.f, 0.f, 0.f, 0.f};
            acc = __builtin_amdgcn_mfma_f32_16x16x32_bf16(a0.v, b0.v, acc, 0, 0, 0);
            acc = __builtin_amdgcn_mfma_f32_16x16x32_bf16(a1.v, b1.v, acc, 0, 0, 0);
            accs[ot] = acc;
        }
        const size_t ybase = ((size_t)r * N + m0) * DD;
        #pragma unroll
        for (int g = 0; g < 4; ++g) {
            int row = quad * 4 + g;
            if (full || m0 + row < N) {
                uint2 p = make_uint2(
                    f2bf(accs[0][g]) | (f2bf(accs[1][g]) << 16),
                    f2bf(accs[2][g]) | (f2bf(accs[3][g]) << 16));
                *(uint2*)(Y + ybase + (size_t)row * DD + 4 * c) = p;
            }
        }
    }
}

// ---------------- aggregate: half-wave per node, permuted-row reads ------------
__global__ __launch_bounds__(256) void k_aggregate(
    const ushort_t* __restrict__ Y, const int* __restrict__ rp,
    const uint2* __restrict__ ep,
    const float* __restrict__ bias, float* __restrict__ out, int N)
{
    const int n = blockIdx.x * 8 + (threadIdx.x >> 5);
    const int lane = threadIdx.x & 31;
    if (n >= N) return;
    const int b = n >> 6, i = n & 63;
    const int beg = rp[b * 65 + i], end = rp[b * 65 + i + 1];

    // permuted columns this lane owns: o' = 2*lane, 2*lane+1
    const int o0 = 2 * lane, o1 = 2 * lane + 1;
    const int col0 = (o0 & 3) * 16 + (o0 >> 2);
    const int col1 = (o1 & 3) * 16 + (o1 >> 2);

    float accx = 0.f, accy = 0.f;
    for (int p0 = beg; p0 < end; p0 += 32) {
        int cnt = end - p0; if (cnt > 32) cnt = 32;
        unsigned pk = 0, ivb = 0;
        if (lane < cnt) { uint2 m = ep[p0 + lane]; pk = m.x; ivb = m.y; }
        for (int jj = 0; jj < cnt; jj += 8) {
            unsigned v[8]; float ivv[8];
            #pragma unroll
            for (int q = 0; q < 8; ++q) {
                int t = (jj + q) & 31;
                unsigned pkj = (unsigned)__shfl((int)pk, t, 32);
                float iv = __uint_as_float((unsigned)__shfl((int)ivb, t, 32));
                ivv[q] = (jj + q < cnt) ? iv : 0.f;
                v[q] = *(const unsigned*)(Y + (size_t)(pkj & 0xFFFFFu) * DD + 2 * lane);
            }
            #pragma unroll
            for (int q = 0; q < 8; ++q) {
                accx = fmaf(bf_lo(v[q]), ivv[q], accx);
                accy = fmaf(bf_hi(v[q]), ivv[q], accy);
            }
        }
    }
    float* op = out + (size_t)n * DD;
    op[col0] = fmaxf(accx + bias[col0], 0.f);
    op[col1] = fmaxf(accy + bias[col1], 0.f);
}

// ---------------- fallback (chunked, atomic; natural layout, self-consistent) --
__global__ __launch_bounds__(256) void k_transform(
    const float* __restrict__ x, const float* __restrict__ W,
    ushort_t* __restrict__ Y, int N, int r_base, int r_cnt, int yr_off)
{
    __shared__ float xt[DD * 128];
    __shared__ float ws[DD * DD];
    const int n0 = blockIdx.x * 128;
    const int tid = threadIdx.x;

    #pragma unroll
    for (int c = 0; c < 8; ++c) {
        int idx = c * 256 + tid;
        int n  = idx >> 4;
        int i4 = (idx & 15) << 2;
        int gn = n0 + n;
        float4 v = make_float4(0.f, 0.f, 0.f, 0.f);
        if (gn < N) v = ((const float4*)(x + (size_t)gn * DD))[idx & 15];
        int n4 = n >> 2, nr = n & 3;
        float vv[4] = {v.x, v.y, v.z, v.w};
        #pragma unroll
        for (int k = 0; k < 4; ++k) {
            int i = i4 + k;
            int swz = (i >> 2) & 7;
            xt[i * 128 + (((n4 ^ swz) << 2) | nr)] = vv[k];
        }
    }

    const int j  = tid & 15;
    const int nq = tid >> 4;

    for (int rr = 0; rr < r_cnt; ++rr) {
        const int r = r_base + blockIdx.y * r_cnt + rr;
        __syncthreads();
        {
            const float4* Wv = (const float4*)(W + (size_t)r * DD * DD);
            float4* wv = (float4*)ws;
            #pragma unroll
            for (int c = 0; c < 4; ++c) wv[c * 256 + tid] = Wv[c * 256 + tid];
        }
        __syncthreads();

        float4 acc[8];
        #pragma unroll
        for (int m = 0; m < 8; ++m) acc[m] = make_float4(0.f, 0.f, 0.f, 0.f);

        #pragma unroll 4
        for (int i = 0; i < DD; ++i) {
            const int swz = (i >> 2) & 7;
            const float4 wv = *(const float4*)&ws[i * DD + 4 * j];
            #pragma unroll
            for (int h = 0; h < 2; ++h) {
                const int col4 = (2 * nq + h) ^ swz;
                const float4 xv = *(const float4*)&xt[i * 128 + (col4 << 2)];
                fma4(acc[4 * h + 0], wv, xv.x);
                fma4(acc[4 * h + 1], wv, xv.y);
                fma4(acc[4 * h + 2], wv, xv.z);
                fma4(acc[4 * h + 3], wv, xv.w);
            }
        }

        const size_t ybase = (size_t)(r - yr_off) * N;
        #pragma unroll
        for (int m = 0; m < 8; ++m) {
            int node = n0 + 8 * nq + 4 * (m >> 2) + (m & 3);
            if (node < N)
                *(uint2*)(Y + (ybase + node) * DD + 4 * j) = pk4(acc[m]);
        }
    }
}

__global__ __launch_bounds__(256) void k_edges(
    const int* __restrict__ ei, const int* __restrict__ et,
    const float* __restrict__ pl, const ushort_t* __restrict__ Y,
    float* __restrict__ aggr, int N, int E, int Etot, int rel_filter)
{
    int sub = threadIdx.x >> 5;
    int lane = threadIdx.x & 31;
    int e = blockIdx.x * 8 + sub;
    if (e >= Etot) return;
    int rt = et[e];
    int yrel = rt;
    if (rel_filter >= 0) { if (rt != rel_filter) return; yrel = 0; }
    int src, dst;
    if (e < E) { src = ei[e]; dst = ei[E + e]; }
    else       { src = dst = e - E; }
    float inv = 1.0f / fmaxf(pl[e], EPSF);
    unsigned v = *(const unsigned*)(Y + ((size_t)yrel * N + src) * DD + 2 * lane);
    atomicAdd(&aggr[(size_t)dst * DD + 2 * lane],     bf_lo(v) * inv);
    atomicAdd(&aggr[(size_t)dst * DD + 2 * lane + 1], bf_hi(v) * inv);
}

__global__ __launch_bounds__(256) void k_bias_relu(
    const float* __restrict__ aggr, const float* __restrict__ bias,
    float* __restrict__ out, int N)
{
    int idx = blockIdx.x * 256 + threadIdx.x;
    if (idx >= N * (DD / 4)) return;
    float4 a = ((const float4*)aggr)[idx];
    int o4 = (idx & 15) * 4;
    a.x = fmaxf(a.x + bias[o4 + 0], 0.f);
    a.y = fmaxf(a.y + bias[o4 + 1], 0.f);
    a.z = fmaxf(a.z + bias[o4 + 2], 0.f);
    a.w = fmaxf(a.w + bias[o4 + 3], 0.f);
    ((float4*)out)[idx] = a;
}

__global__ __launch_bounds__(256) void k_zero(float* __restrict__ p, size_t n)
{
    size_t i = (size_t)blockIdx.x * 256 + threadIdx.x;
    size_t stride = (size_t)gridDim.x * 256;
    for (; i < n; i += stride) p[i] = 0.f;
}

extern "C" void kernel_launch(void* const* d_in, const int* in_sizes, int n_in,
                              void* d_out, int out_size, void* d_ws, size_t ws_size,
                              hipStream_t stream)
{
    const float* x  = (const float*)d_in[0];
    const int*   ei = (const int*)d_in[1];
    const int*   et = (const int*)d_in[2];
    const float* pl = (const float*)d_in[3];
    const float* W1 = (const float*)d_in[4];
    const float* b1 = (const float*)d_in[5];
    const float* W2 = (const float*)d_in[6];
    const float* b2 = (const float*)d_in[7];
    float* out = (float*)d_out;

    const int N = in_sizes[0] / DD;
    const int E = in_sizes[1] / 2;
    const size_t ndf = (size_t)N * DD;
    const size_t wb_elems = (size_t)RR * 2 * 4 * 64 * 8;   // 65536 ushorts
    const int B = (N + 63) / 64;                            // 64-node buckets

    int avg = (E + B - 1) / B;
    int cap = avg + 8 * (int)sqrtf((float)avg) + 128;       // + self-loop head
    cap = (cap + 3) & ~3;

    char* wsb = (char*)d_ws;
    ushort_t* Y   = (ushort_t*)wsb;                          // RR*ndf bf16
    float* aggr1  = (float*)(wsb + (size_t)RR * ndf * 2);    // ndf fp32 (hidden)
    ushort_t* Wb1 = (ushort_t*)((char*)aggr1 + ndf * 4);     // 128 KB
    ushort_t* Wb2 = Wb1 + wb_elems;                          // 128 KB
    uint2* ep     = (uint2*)(Wb2 + wb_elems);                // B*cap
    uint2* ep2    = ep + (size_t)B * cap;                    // B*cap
    int* cursor   = (int*)(ep2 + (size_t)B * cap);           // B
    int* rp       = cursor + B;                              // B*65

    const size_t need_main = (size_t)RR * ndf * 2 + ndf * 4 + wb_elems * 4 +
        (size_t)B * cap * 16 + ((size_t)B * 66) * 4;
    const bool main_ok = (ws_size >= need_main) && (N <= 65535) && (B <= 1024);

    if (main_ok) {
        const int gBin = (E + BINCH - 1) / BINCH;
        k_prep<<<(16384 + B + N + 255) / 256, 256, 0, stream>>>(
            W1, W2, Wb1, Wb2, cursor, ep, et, pl, B, cap, N, E);
        k_bin<<<gBin, 256, 0, stream>>>(ei, et, pl, cursor, ep, E, B, N, cap);
        k_sortb<<<B, 256, 0, stream>>>(ep, cursor, ep2, rp, B, cap);

        const int gT = (N + 63) / 64;
        const int gA = (N + 7) / 8;
        for (int layer = 0; layer < 2; ++layer) {
            const float* xin   = layer ? aggr1 : x;
            const ushort_t* Wb = layer ? Wb2 : Wb1;
            const float* bias  = layer ? b2 : b1;
            float* dest        = layer ? out : aggr1;
            k_transform_mfma<<<gT, 256, 0, stream>>>(xin, Wb, Y, N);
            k_aggregate<<<gA, 256, 0, stream>>>(Y, rp, ep2, bias, dest, N);
        }
        return;
    }

    // chunked fallback: Yc = ndf bf16, aggr = ndf fp32
    ushort_t* Yc = (ushort_t*)wsb;
    float* ag    = (float*)(wsb + ndf * 2);
    const int gx     = (N + 127) / 128;
    const int gEdgeT = (E + N + 7) / 8;
    const int gQuad  = (N * (DD / 4) + 255) / 256;
    float* hid = ag;

    for (int layer = 0; layer < 2; ++layer) {
        const float* xin  = layer ? hid : x;
        const float* W    = layer ? W2 : W1;
        const float* bias = layer ? b2 : b1;
        float* aggr       = layer ? out : ag;
        k_zero<<<1024, 256, 0, stream>>>(aggr, ndf);
        for (int r = 0; r < RR; ++r) {
            k_transform<<<dim3(gx, 1), 256, 0, stream>>>(xin, W, Yc, N, r, 1, r);
            k_edges<<<gEdgeT, 256, 0, stream>>>(ei, et, pl, Yc, aggr, N, E, E + N, r);
        }
        k_bias_relu<<<gQuad, 256, 0, stream>>>(aggr, bias, layer ? out : hid, N);
    }
}